// Round 6
// baseline (580.166 us; speedup 1.0000x reference)
//
#include <hip/hip_runtime.h>
#include <hip/hip_bf16.h>

#define NN 8192
#define CH 256

typedef float f32x4 __attribute__((ext_vector_type(4)));
typedef __bf16 bf16x8 __attribute__((ext_vector_type(8)));

union FragU { uint4 u; bf16x8 h; };

static __device__ __forceinline__ unsigned short f2bf(float f) {
  union { float f; unsigned int u; } v; v.f = f;
  unsigned int x = v.u;
  return (unsigned short)((x + 0x7fffu + ((x >> 16) & 1u)) >> 16);  // RNE
}

#if defined(__has_builtin)
#if __has_builtin(__builtin_amdgcn_global_load_lds)
#define HAVE_GLL 1
#endif
#endif

#ifdef HAVE_GLL
// async 16B/lane global->LDS. LDS dest = wave-uniform base + lane*16 (linear).
static __device__ __forceinline__ void gload16(const void* g, void* l) {
  __builtin_amdgcn_global_load_lds(
      (const __attribute__((address_space(1))) void*)(unsigned long long)(g),
      (__attribute__((address_space(3))) void*)(unsigned int)(unsigned long long)(l),
      16, 0, 0);
}
#endif

static __device__ __forceinline__ unsigned int cvtpk(float a, float b) {
  unsigned int r;  // lo16 = bf16(a), hi16 = bf16(b), RNE
  asm("v_cvt_pk_bf16_f32 %0, %1, %2" : "=v"(r) : "v"(a), "v"(b));
  return r;
}

#define WAITV(n) asm volatile("s_waitcnt vmcnt(" #n ")" ::: "memory")
#define BARRIER() __builtin_amdgcn_s_barrier()

// ---------------- kernel 1: HT[j][k] = bf16(d[k]*H[k][j]), WT[j][c] = bf16(W[c][j])
__global__ __launch_bounds__(256) void k_prep(const float* __restrict__ Hm,
                                              const float* __restrict__ Dm,
                                              const float* __restrict__ Wm,
                                              unsigned short* __restrict__ HT,
                                              unsigned short* __restrict__ WT) {
  __shared__ float tile[64][65];
  int bx = blockIdx.x, t = threadIdx.x;
  bool isH = bx < 512;
  int b = isH ? bx : bx - 512;
  int r0 = (b >> 2) * 64;
  int j0 = (b & 3) * 64;
  const float* src = isH ? Hm : Wm;

  int r = t >> 2;
  int cq = (t & 3) * 16;
  float dval = isH ? rsqrtf(Dm[(size_t)(r0 + r) * (NN + 1)]) : 1.0f;
  const float* p = src + (size_t)(r0 + r) * CH + j0 + cq;
#pragma unroll
  for (int u = 0; u < 4; ++u) {
    float4 v = *(const float4*)(p + u * 4);
    tile[r][cq + u * 4 + 0] = v.x * dval;
    tile[r][cq + u * 4 + 1] = v.y * dval;
    tile[r][cq + u * 4 + 2] = v.z * dval;
    tile[r][cq + u * 4 + 3] = v.w * dval;
  }
  __syncthreads();
  int j = t >> 2;
  int kq = (t & 3) * 16;
  __align__(16) unsigned short ov[16];
#pragma unroll
  for (int i = 0; i < 16; ++i) ov[i] = f2bf(tile[kq + i][j]);
  unsigned short* dst = isH ? (HT + (size_t)(j0 + j) * NN + r0 + kq)
                            : (WT + (size_t)(j0 + j) * CH + r0 + kq);
  *(uint4*)dst = *(uint4*)ov;
  *(uint4*)(dst + 8) = *(uint4*)(ov + 8);
}

// ---------------- fused kernel: out = diag(d) * (bf16(A) @ HT^T) @ W
// BM=32, BN=256 (full), SK=1: grid 256 blocks x 512 threads (8 waves, 1 block/CU).
// Each wave owns a 32x32 output sub-tile (2x2 16x16 frags) -> no duplicated B reads.
// A staged fp32 via global_load_lds (16B, one op/thread/tile) into XOR-swizzled
// double-buffered LDS; bf16 conversion at frag read (v_cvt_pk_bf16_f32).
// B frags straight from L2-resident HT (4 MiB = per-XCD L2). Counted vmcnt(5):
// next tile's 1 stage + 4 B loads stay in flight across barriers.
// Epilogue fuses the second GEMM: G=d[i]*acc -> bf16 in LDS, out = G @ W via WT.
// Eliminates the 256 MB fp32 P round-trip of the split-K version entirely.
__global__ __launch_bounds__(512, 1) void k_fused(const float* __restrict__ A,
                                                  const float* __restrict__ Dm,
                                                  const unsigned short* __restrict__ HT,
                                                  const unsigned short* __restrict__ WT,
                                                  float* __restrict__ out) {
  constexpr int NIT = NN / 64;          // 128 K-tiles
  __shared__ float Asf[2][2048];        // [buf][32 rows][64 cols] fp32, 16B-window XOR swizzle
  __shared__ unsigned short Gs[32][264];
  __shared__ float dsh[32];
  const int bx = blockIdx.x, t = threadIdx.x, l = t & 63, w = t >> 6;
  const int lan = l & 15, quad = l >> 4;
  const int i0 = bx * 32;

  // Staging: thread t covers LDS row t>>4, 16B window t&15; source window
  // pre-XOR'd with (row&7) so the linear LDS write lands swizzled.
  const char* Ag = (const char*)A + (size_t)(i0 + (t >> 4)) * NN * 4
                   + (size_t)(((t & 15) ^ ((t >> 4) & 7)) * 16);
  const unsigned short* Bb = HT + (size_t)(w * 32 + lan) * NN + quad * 8;

  if (t < 32) dsh[t] = rsqrtf(Dm[(size_t)(i0 + t) * (NN + 1)]);

  FragU b0[4], b1[4];
  f32x4 acc[2][2];
#pragma unroll
  for (int mt = 0; mt < 2; ++mt)
#pragma unroll
    for (int nt = 0; nt < 2; ++nt)
#pragma unroll
      for (int c = 0; c < 4; ++c) acc[mt][nt][c] = 0.0f;

  auto stage = [&](int kt, int buf) {
#ifdef HAVE_GLL
    gload16(Ag + (size_t)kt * 256, (char*)&Asf[buf][0] + t * 16);
#else
    float4 tv = *(const float4*)(Ag + (size_t)kt * 256);
    *(float4*)((char*)&Asf[buf][0] + t * 16) = tv;
    asm volatile("s_waitcnt lgkmcnt(0)" ::: "memory");
#endif
  };

  auto loadB = [&](FragU (&dst)[4], int kt) {
    const unsigned short* p = Bb + (size_t)kt * 64;
#pragma unroll
    for (int ss = 0; ss < 2; ++ss)
#pragma unroll
      for (int nt = 0; nt < 2; ++nt)
        dst[ss * 2 + nt].u = *(const uint4*)(p + (size_t)nt * 16 * NN + ss * 32);
  };

  const int sw = (lan & 7) * 16;
  auto compute = [&](FragU (&b)[4], const char* Ab) {
#pragma unroll
    for (int ss = 0; ss < 2; ++ss) {
      FragU af[2];
#pragma unroll
      for (int mt = 0; mt < 2; ++mt) {
        const char* rp = Ab + (mt * 16 + lan) * 256;
        const int x = ss * 128 + quad * 32;
        float4 va = *(const float4*)(rp + ((x) ^ sw));
        float4 vb = *(const float4*)(rp + ((x + 16) ^ sw));
        af[mt].u.x = cvtpk(va.x, va.y);
        af[mt].u.y = cvtpk(va.z, va.w);
        af[mt].u.z = cvtpk(vb.x, vb.y);
        af[mt].u.w = cvtpk(vb.z, vb.w);
      }
#pragma unroll
      for (int mt = 0; mt < 2; ++mt)
#pragma unroll
        for (int nt = 0; nt < 2; ++nt)
          acc[mt][nt] = __builtin_amdgcn_mfma_f32_16x16x32_bf16(af[mt].h, b[ss * 2 + nt].h,
                                                                acc[mt][nt], 0, 0, 0);
    }
  };

  stage(0, 0);
  loadB(b0, 0);
#pragma unroll 1
  for (int kt = 0; kt < NIT; kt += 2) {
    // even tile kt (buf0): issue kt+1, keep its 5 loads in flight
    stage(kt + 1, 1);
    loadB(b1, kt + 1);
    WAITV(5);        // tile kt's 1 stage + 4 B loads retired; 5 newest stay in flight
    BARRIER();       // all waves' stage(kt) portions visible
    compute(b0, (const char*)&Asf[0][0]);
    BARRIER();       // protects buf0 from next overwrite
    // odd tile kt+1 (buf1)
    if (kt + 2 < NIT) {
      stage(kt + 2, 0);
      loadB(b0, kt + 2);
      WAITV(5);
    } else {
      WAITV(0);
    }
    BARRIER();
    compute(b1, (const char*)&Asf[1][0]);
    BARRIER();
  }

  // epilogue: G = d[i] * acc -> bf16 LDS, then out[32][256] = G @ W (via WT)
#pragma unroll
  for (int mt = 0; mt < 2; ++mt)
#pragma unroll
    for (int nt = 0; nt < 2; ++nt)
#pragma unroll
      for (int r = 0; r < 4; ++r) {
        const int row = mt * 16 + quad * 4 + r;
        Gs[row][w * 32 + nt * 16 + lan] = f2bf(acc[mt][nt][r] * dsh[row]);
      }
  __syncthreads();

  const int r0w = (w & 1) * 16, j0c = (w >> 1) * 64;
  f32x4 o[4];
#pragma unroll
  for (int nt = 0; nt < 4; ++nt)
#pragma unroll
    for (int c = 0; c < 4; ++c) o[nt][c] = 0.0f;
#pragma unroll
  for (int ks = 0; ks < 8; ++ks) {
    FragU af;
    af.u = *(const uint4*)&Gs[r0w + lan][ks * 32 + quad * 8];
#pragma unroll
    for (int nt = 0; nt < 4; ++nt) {
      FragU bw;
      bw.u = *(const uint4*)&WT[(size_t)(j0c + nt * 16 + lan) * CH + ks * 32 + quad * 8];
      o[nt] = __builtin_amdgcn_mfma_f32_16x16x32_bf16(af.h, bw.h, o[nt], 0, 0, 0);
    }
  }
#pragma unroll
  for (int nt = 0; nt < 4; ++nt)
#pragma unroll
    for (int r = 0; r < 4; ++r)
      out[(size_t)(i0 + r0w + quad * 4 + r) * CH + j0c + nt * 16 + lan] = o[nt][r];
}

extern "C" void kernel_launch(void* const* d_in, const int* in_sizes, int n_in,
                              void* d_out, int out_size, void* d_ws, size_t ws_size,
                              hipStream_t stream) {
  const float* A  = (const float*)d_in[0];
  const float* Dm = (const float*)d_in[1];
  const float* Hm = (const float*)d_in[2];
  const float* Wm = (const float*)d_in[3];
  float* out = (float*)d_out;
  char* ws = (char*)d_ws;
  unsigned short* HT = (unsigned short*)ws;                       // 4 MiB
  unsigned short* WT = (unsigned short*)(ws + (size_t)4194304);   // 128 KiB

  hipLaunchKernelGGL(k_prep, dim3(528), dim3(256), 0, stream, Hm, Dm, Wm, HT, WT);
  hipLaunchKernelGGL(k_fused, dim3(256), dim3(512), 0, stream, A, Dm, HT, WT, out);
}

// Round 11
// 543.432 us; speedup vs baseline: 1.0676x; 1.0676x over previous
//
#include <hip/hip_runtime.h>
#include <hip/hip_bf16.h>

#define NN 8192
#define CH 256

typedef float f32x4 __attribute__((ext_vector_type(4)));
typedef __bf16 bf16x8 __attribute__((ext_vector_type(8)));

union FragU { uint4 u; bf16x8 h; };

static __device__ __forceinline__ unsigned short f2bf(float f) {
  union { float f; unsigned int u; } v; v.f = f;
  unsigned int x = v.u;
  return (unsigned short)((x + 0x7fffu + ((x >> 16) & 1u)) >> 16);  // RNE
}

static __device__ __forceinline__ unsigned int cvtpk(float a, float b) {
  unsigned int r;  // lo16 = bf16(a), hi16 = bf16(b), RNE
  asm("v_cvt_pk_bf16_f32 %0, %1, %2" : "=v"(r) : "v"(a), "v"(b));
  return r;
}

#define WAITV(n) asm volatile("s_waitcnt vmcnt(" #n ")" ::: "memory")
#define LGKM0()  asm volatile("s_waitcnt lgkmcnt(0)" ::: "memory")
#define BARRIER() __builtin_amdgcn_s_barrier()
#define FENCE()  asm volatile("" ::: "memory")

// ---------------- kernel 1: HT[j][k] = bf16(d[k]*H[k][j]), WT[j][c] = bf16(W[c][j])
__global__ __launch_bounds__(256) void k_prep(const float* __restrict__ Hm,
                                              const float* __restrict__ Dm,
                                              const float* __restrict__ Wm,
                                              unsigned short* __restrict__ HT,
                                              unsigned short* __restrict__ WT) {
  __shared__ float tile[64][65];
  int bx = blockIdx.x, t = threadIdx.x;
  bool isH = bx < 512;
  int b = isH ? bx : bx - 512;
  int r0 = (b >> 2) * 64;
  int j0 = (b & 3) * 64;
  const float* src = isH ? Hm : Wm;

  int r = t >> 2;
  int cq = (t & 3) * 16;
  float dval = isH ? rsqrtf(Dm[(size_t)(r0 + r) * (NN + 1)]) : 1.0f;
  const float* p = src + (size_t)(r0 + r) * CH + j0 + cq;
#pragma unroll
  for (int u = 0; u < 4; ++u) {
    float4 v = *(const float4*)(p + u * 4);
    tile[r][cq + u * 4 + 0] = v.x * dval;
    tile[r][cq + u * 4 + 1] = v.y * dval;
    tile[r][cq + u * 4 + 2] = v.z * dval;
    tile[r][cq + u * 4 + 3] = v.w * dval;
  }
  __syncthreads();
  int j = t >> 2;
  int kq = (t & 3) * 16;
  __align__(16) unsigned short ov[16];
#pragma unroll
  for (int i = 0; i < 16; ++i) ov[i] = f2bf(tile[kq + i][j]);
  unsigned short* dst = isH ? (HT + (size_t)(j0 + j) * NN + r0 + kq)
                            : (WT + (size_t)(j0 + j) * CH + r0 + kq);
  *(uint4*)dst = *(uint4*)ov;
  *(uint4*)(dst + 8) = *(uint4*)(ov + 8);
}

// ---------------- fused kernel: out = diag(d) * (bf16(A) @ HT^T) @ W
// BM=32, BN=256, grid 256 x 512 threads (8 waves; wave w owns cols w*32..+32).
// Round-6 fix: A is reg-staged (1 dwordx4/thread), converted fp32->bf16 ONCE
// (2 cvtpk/thread), ds_write'd 8B into a bf16 LDS tile with XOR swizzle
// (half_idx ^= (row&7)*8). Kills the x8 LDS-read + x8 cvt amplification that
// made the fp32-LDS version 4087 cyc/tile (950 VALU + ~1030 LDS cyc/tile/CU).
// Quad-buffered 4KB A-tiles -> ONE barrier per tile (write target is 2+
// barriers from any reader). A depth-2 in regs (2 float4 sets by tile parity),
// B depth-1 from L2-hot HT. Counted vmcnt: entry queue [A(k+1), B(k)x4, A(k+2)]
// -> WAITV(5) retires A(k+1); after issuing B(k+1),A(k+3): WAITV(6) retires
// B(k)x4 leaving both A prefetches in flight.
__global__ __launch_bounds__(512, 1) void k_fused(const float* __restrict__ A,
                                                  const float* __restrict__ Dm,
                                                  const unsigned short* __restrict__ HT,
                                                  const unsigned short* __restrict__ WT,
                                                  float* __restrict__ out) {
  constexpr int NIT = NN / 64;              // 128 K-tiles
  __shared__ unsigned short Asb[4][2048];   // 4 bufs x [32 rows][64 halfs] bf16, swizzled
  __shared__ unsigned short Gs[32][264];
  __shared__ float dsh[32];
  const int t = threadIdx.x, l = t & 63, w = t >> 6;
  const int lan = l & 15, quad = l >> 4;
  const int i0 = blockIdx.x * 32;

  const int arow = t >> 4;  // staging row 0..31
  const int aswr = arow * 64 + (((t & 15) * 4) ^ ((arow & 7) * 8));  // swizzled half idx
  const char* Ag = (const char*)A + (size_t)(i0 + arow) * NN * 4 + (t & 15) * 16;
  const unsigned short* Bb = HT + (size_t)(w * 32 + lan) * NN + quad * 8;

  if (t < 32) dsh[t] = rsqrtf(Dm[(size_t)(i0 + t) * (NN + 1)]);

  FragU bb0[4], bb1[4];
  float4 aS0, aS1;          // A staging reg sets: A(j) lives in set (j&1)
  f32x4 acc[2][2];
#pragma unroll
  for (int mt = 0; mt < 2; ++mt)
#pragma unroll
    for (int nt = 0; nt < 2; ++nt)
#pragma unroll
      for (int c = 0; c < 4; ++c) acc[mt][nt][c] = 0.0f;

  auto aload = [&](float4& dst, int kt) {
    dst = *(const float4*)(Ag + (size_t)kt * 256);
  };
  auto cvtwrite = [&](const float4& v, int bi) {
    uint2 pk;
    pk.x = cvtpk(v.x, v.y);
    pk.y = cvtpk(v.z, v.w);
    *(uint2*)&Asb[bi][aswr] = pk;
  };
  auto loadB = [&](FragU (&dst)[4], int kt) {
    const unsigned short* p = Bb + (size_t)kt * 64;
#pragma unroll
    for (int ss = 0; ss < 2; ++ss)
#pragma unroll
      for (int nt = 0; nt < 2; ++nt)
        dst[ss * 2 + nt].u = *(const uint4*)(p + (size_t)nt * 16 * NN + ss * 32);
  };
  auto compute = [&](FragU (&b)[4], const unsigned short* Ab) {
#pragma unroll
    for (int ss = 0; ss < 2; ++ss) {
      FragU af[2];
#pragma unroll
      for (int mt = 0; mt < 2; ++mt) {
        const int row = mt * 16 + lan;
        af[mt].u = *(const uint4*)&Ab[row * 64 + ((ss * 32 + quad * 8) ^ ((lan & 7) * 8))];
      }
#pragma unroll
      for (int mt = 0; mt < 2; ++mt)
#pragma unroll
        for (int nt = 0; nt < 2; ++nt)
          acc[mt][nt] = __builtin_amdgcn_mfma_f32_16x16x32_bf16(af[mt].h, b[ss * 2 + nt].h,
                                                                acc[mt][nt], 0, 0, 0);
    }
  };

  // prologue: queue becomes [A(1), B(0)x4, A(2)]; buf0 written.
  aload(aS0, 0);
  aload(aS1, 1);
  loadB(bb0, 0);
  WAITV(5);             // A(0) ready
  cvtwrite(aS0, 0);
  aload(aS0, 2);

#pragma unroll 1
  for (int kt = 0; kt + 5 < NIT; kt += 2) {
    // tile kt: consume A(kt+1)[aS1]; issue B(kt+1)->bb1, A(kt+3)->aS1
    WAITV(5);
    cvtwrite(aS1, (kt + 1) & 3);
    loadB(bb1, kt + 1);
    aload(aS1, kt + 3);
    WAITV(6);
    LGKM0(); BARRIER(); FENCE();
    compute(bb0, &Asb[kt & 3][0]);
    // tile kt+1: consume A(kt+2)[aS0]; issue B(kt+2)->bb0, A(kt+4)->aS0
    WAITV(5);
    cvtwrite(aS0, (kt + 2) & 3);
    loadB(bb0, kt + 2);
    aload(aS0, kt + 4);
    WAITV(6);
    LGKM0(); BARRIER(); FENCE();
    compute(bb1, &Asb[(kt + 1) & 3][0]);
  }

  // peeled tail: tiles NIT-4 .. NIT-1 (124..127)
  {
    // tile 124: entry [A(125), B(124)x4, A(126)]
    WAITV(5);
    cvtwrite(aS1, (NIT - 3) & 3);        // buf[125&3]=1
    loadB(bb1, NIT - 3);                 // B(125)
    aload(aS1, NIT - 1);                 // A(127)
    WAITV(6);
    LGKM0(); BARRIER(); FENCE();
    compute(bb0, &Asb[(NIT - 4) & 3][0]);
    // tile 125: entry [A(126), B(125)x4, A(127)]
    WAITV(5);
    cvtwrite(aS0, (NIT - 2) & 3);        // buf[126&3]=2
    loadB(bb0, NIT - 2);                 // B(126)
    WAITV(5);                            // retire B(125)
    LGKM0(); BARRIER(); FENCE();
    compute(bb1, &Asb[(NIT - 3) & 3][0]);
    // tile 126: entry [A(127), B(126)x4]
    WAITV(4);
    cvtwrite(aS1, (NIT - 1) & 3);        // buf[127&3]=3
    loadB(bb1, NIT - 1);                 // B(127)
    WAITV(4);                            // retire B(126)
    LGKM0(); BARRIER(); FENCE();
    compute(bb0, &Asb[(NIT - 2) & 3][0]);
    // tile 127: entry [B(127)x4]
    WAITV(0);
    LGKM0(); BARRIER(); FENCE();
    compute(bb1, &Asb[(NIT - 1) & 3][0]);
  }

  // epilogue: G = d[i] * acc -> bf16 LDS, then out[32][256] = G @ W (via WT)
  LGKM0(); BARRIER(); FENCE();
#pragma unroll
  for (int mt = 0; mt < 2; ++mt)
#pragma unroll
    for (int nt = 0; nt < 2; ++nt)
#pragma unroll
      for (int r = 0; r < 4; ++r) {
        const int row = mt * 16 + quad * 4 + r;
        Gs[row][w * 32 + nt * 16 + lan] = f2bf(acc[mt][nt][r] * dsh[row]);
      }
  __syncthreads();

  const int r0w = (w & 1) * 16, j0c = (w >> 1) * 64;
  f32x4 o[4];
#pragma unroll
  for (int nt = 0; nt < 4; ++nt)
#pragma unroll
    for (int c = 0; c < 4; ++c) o[nt][c] = 0.0f;
#pragma unroll
  for (int ks = 0; ks < 8; ++ks) {
    FragU af;
    af.u = *(const uint4*)&Gs[r0w + lan][ks * 32 + quad * 8];
#pragma unroll
    for (int nt = 0; nt < 4; ++nt) {
      FragU bw;
      bw.u = *(const uint4*)&WT[(size_t)(j0c + nt * 16 + lan) * CH + ks * 32 + quad * 8];
      o[nt] = __builtin_amdgcn_mfma_f32_16x16x32_bf16(af.h, bw.h, o[nt], 0, 0, 0);
    }
  }
#pragma unroll
  for (int nt = 0; nt < 4; ++nt)
#pragma unroll
    for (int r = 0; r < 4; ++r)
      out[(size_t)(i0 + r0w + quad * 4 + r) * CH + j0c + nt * 16 + lan] = o[nt][r];
}

extern "C" void kernel_launch(void* const* d_in, const int* in_sizes, int n_in,
                              void* d_out, int out_size, void* d_ws, size_t ws_size,
                              hipStream_t stream) {
  const float* A  = (const float*)d_in[0];
  const float* Dm = (const float*)d_in[1];
  const float* Hm = (const float*)d_in[2];
  const float* Wm = (const float*)d_in[3];
  float* out = (float*)d_out;
  char* ws = (char*)d_ws;
  unsigned short* HT = (unsigned short*)ws;                       // 4 MiB
  unsigned short* WT = (unsigned short*)(ws + (size_t)4194304);   // 128 KiB

  hipLaunchKernelGGL(k_prep, dim3(528), dim3(256), 0, stream, Hm, Dm, Wm, HT, WT);
  hipLaunchKernelGGL(k_fused, dim3(256), dim3(512), 0, stream, A, Dm, HT, WT, out);
}

// Round 14
// 538.882 us; speedup vs baseline: 1.0766x; 1.0084x over previous
//
#include <hip/hip_runtime.h>
#include <hip/hip_bf16.h>

#define NN 8192
#define CH 256

typedef float f32x4 __attribute__((ext_vector_type(4)));
typedef __bf16 bf16x8 __attribute__((ext_vector_type(8)));

union FragU { uint4 u; bf16x8 h; };

static __device__ __forceinline__ unsigned short f2bf(float f) {
  union { float f; unsigned int u; } v; v.f = f;
  unsigned int x = v.u;
  return (unsigned short)((x + 0x7fffu + ((x >> 16) & 1u)) >> 16);  // RNE
}

static __device__ __forceinline__ unsigned int cvtpk(float a, float b) {
  unsigned int r;  // lo16 = bf16(a), hi16 = bf16(b), RNE
  asm("v_cvt_pk_bf16_f32 %0, %1, %2" : "=v"(r) : "v"(a), "v"(b));
  return r;
}

#if defined(__has_builtin)
#if __has_builtin(__builtin_nontemporal_load)
#define HAVE_NT 1
#endif
#endif

#define WAITV(n) asm volatile("s_waitcnt vmcnt(" #n ")" ::: "memory")
#define LGKM0()  asm volatile("s_waitcnt lgkmcnt(0)" ::: "memory")
#define BARRIER() __builtin_amdgcn_s_barrier()
#define FENCE()  asm volatile("" ::: "memory")

// ---------------- kernel 1: HT[j][k] = bf16(d[k]*H[k][j]), WT[j][c] = bf16(W[c][j])
__global__ __launch_bounds__(256) void k_prep(const float* __restrict__ Hm,
                                              const float* __restrict__ Dm,
                                              const float* __restrict__ Wm,
                                              unsigned short* __restrict__ HT,
                                              unsigned short* __restrict__ WT) {
  __shared__ float tile[64][65];
  int bx = blockIdx.x, t = threadIdx.x;
  bool isH = bx < 512;
  int b = isH ? bx : bx - 512;
  int r0 = (b >> 2) * 64;
  int j0 = (b & 3) * 64;
  const float* src = isH ? Hm : Wm;

  int r = t >> 2;
  int cq = (t & 3) * 16;
  float dval = isH ? rsqrtf(Dm[(size_t)(r0 + r) * (NN + 1)]) : 1.0f;
  const float* p = src + (size_t)(r0 + r) * CH + j0 + cq;
#pragma unroll
  for (int u = 0; u < 4; ++u) {
    float4 v = *(const float4*)(p + u * 4);
    tile[r][cq + u * 4 + 0] = v.x * dval;
    tile[r][cq + u * 4 + 1] = v.y * dval;
    tile[r][cq + u * 4 + 2] = v.z * dval;
    tile[r][cq + u * 4 + 3] = v.w * dval;
  }
  __syncthreads();
  int j = t >> 2;
  int kq = (t & 3) * 16;
  __align__(16) unsigned short ov[16];
#pragma unroll
  for (int i = 0; i < 16; ++i) ov[i] = f2bf(tile[kq + i][j]);
  unsigned short* dst = isH ? (HT + (size_t)(j0 + j) * NN + r0 + kq)
                            : (WT + (size_t)(j0 + j) * CH + r0 + kq);
  *(uint4*)dst = *(uint4*)ov;
  *(uint4*)(dst + 8) = *(uint4*)(ov + 8);
}

// ---------------- fused kernel: out = diag(d) * (bf16(A) @ HT^T) @ W
// BM=32, BN=256, grid 256 x 512 threads (8 waves; wave w owns cols w*32..+32).
// Round-11 model closure: per-tile 3446 cyc measured == 3428 cyc predicted if
// the 1 GiB aggregate B-read (256 blocks x full 4 MiB HT) is served by the L3
// path at the ~5.6 TB/s effective ceiling. HT can't stay in L2 (4 MiB = whole
// per-XCD L2) because the A stream (268 MB through each L2, ZERO reuse) evicts
// it. Round-11 change: A staging loads are NON-TEMPORAL (nt) -> A stops
// thrashing L2, HT becomes L2-resident (B reads keep it MRU), B path moves to
// L2 (~585 cyc/tile/XCD) and the A HBM stream (~800 cyc/tile) becomes the
// critical path. Everything else identical to round 6 (audited 3x).
__global__ __launch_bounds__(512, 1) void k_fused(const float* __restrict__ A,
                                                  const float* __restrict__ Dm,
                                                  const unsigned short* __restrict__ HT,
                                                  const unsigned short* __restrict__ WT,
                                                  float* __restrict__ out) {
  constexpr int NIT = NN / 64;              // 128 K-tiles
  __shared__ unsigned short Asb[4][2048];   // 4 bufs x [32 rows][64 halfs] bf16, swizzled
  __shared__ unsigned short Gs[32][264];
  __shared__ float dsh[32];
  const int t = threadIdx.x, l = t & 63, w = t >> 6;
  const int lan = l & 15, quad = l >> 4;
  const int i0 = blockIdx.x * 32;

  const int arow = t >> 4;  // staging row 0..31
  const int aswr = arow * 64 + (((t & 15) * 4) ^ ((arow & 7) * 8));  // swizzled half idx
  const char* Ag = (const char*)A + (size_t)(i0 + arow) * NN * 4 + (t & 15) * 16;
  const unsigned short* Bb = HT + (size_t)(w * 32 + lan) * NN + quad * 8;

  if (t < 32) dsh[t] = rsqrtf(Dm[(size_t)(i0 + t) * (NN + 1)]);

  FragU bb0[4], bb1[4];
  f32x4 aS0, aS1;           // A staging reg sets: A(j) lives in set (j&1)
  f32x4 acc[2][2];
#pragma unroll
  for (int mt = 0; mt < 2; ++mt)
#pragma unroll
    for (int nt = 0; nt < 2; ++nt)
#pragma unroll
      for (int c = 0; c < 4; ++c) acc[mt][nt][c] = 0.0f;

  auto aload = [&](f32x4& dst, int kt) {
#ifdef HAVE_NT
    dst = __builtin_nontemporal_load((const f32x4*)(Ag + (size_t)kt * 256));
#else
    dst = *(const f32x4*)(Ag + (size_t)kt * 256);
#endif
  };
  auto cvtwrite = [&](const f32x4& v, int bi) {
    uint2 pk;
    pk.x = cvtpk(v[0], v[1]);
    pk.y = cvtpk(v[2], v[3]);
    *(uint2*)&Asb[bi][aswr] = pk;
  };
  auto loadB = [&](FragU (&dst)[4], int kt) {
    const unsigned short* p = Bb + (size_t)kt * 64;
#pragma unroll
    for (int ss = 0; ss < 2; ++ss)
#pragma unroll
      for (int nt = 0; nt < 2; ++nt)
        dst[ss * 2 + nt].u = *(const uint4*)(p + (size_t)nt * 16 * NN + ss * 32);
  };
  auto compute = [&](FragU (&b)[4], const unsigned short* Ab) {
#pragma unroll
    for (int ss = 0; ss < 2; ++ss) {
      FragU af[2];
#pragma unroll
      for (int mt = 0; mt < 2; ++mt) {
        const int row = mt * 16 + lan;
        af[mt].u = *(const uint4*)&Ab[row * 64 + ((ss * 32 + quad * 8) ^ ((lan & 7) * 8))];
      }
#pragma unroll
      for (int mt = 0; mt < 2; ++mt)
#pragma unroll
        for (int nt = 0; nt < 2; ++nt)
          acc[mt][nt] = __builtin_amdgcn_mfma_f32_16x16x32_bf16(af[mt].h, b[ss * 2 + nt].h,
                                                                acc[mt][nt], 0, 0, 0);
    }
  };

  // prologue: queue becomes [A(1), B(0)x4, A(2)]; buf0 written.
  aload(aS0, 0);
  aload(aS1, 1);
  loadB(bb0, 0);
  WAITV(5);             // A(0) ready
  cvtwrite(aS0, 0);
  aload(aS0, 2);

#pragma unroll 1
  for (int kt = 0; kt + 5 < NIT; kt += 2) {
    // tile kt: consume A(kt+1)[aS1]; issue B(kt+1)->bb1, A(kt+3)->aS1
    WAITV(5);
    cvtwrite(aS1, (kt + 1) & 3);
    loadB(bb1, kt + 1);
    aload(aS1, kt + 3);
    WAITV(6);
    LGKM0(); BARRIER(); FENCE();
    compute(bb0, &Asb[kt & 3][0]);
    // tile kt+1: consume A(kt+2)[aS0]; issue B(kt+2)->bb0, A(kt+4)->aS0
    WAITV(5);
    cvtwrite(aS0, (kt + 2) & 3);
    loadB(bb0, kt + 2);
    aload(aS0, kt + 4);
    WAITV(6);
    LGKM0(); BARRIER(); FENCE();
    compute(bb1, &Asb[(kt + 1) & 3][0]);
  }

  // peeled tail: tiles NIT-4 .. NIT-1 (124..127)
  {
    // tile 124: entry [A(125), B(124)x4, A(126)]
    WAITV(5);
    cvtwrite(aS1, (NIT - 3) & 3);        // buf[125&3]=1
    loadB(bb1, NIT - 3);                 // B(125)
    aload(aS1, NIT - 1);                 // A(127)
    WAITV(6);
    LGKM0(); BARRIER(); FENCE();
    compute(bb0, &Asb[(NIT - 4) & 3][0]);
    // tile 125: entry [A(126), B(125)x4, A(127)]
    WAITV(5);
    cvtwrite(aS0, (NIT - 2) & 3);        // buf[126&3]=2
    loadB(bb0, NIT - 2);                 // B(126)
    WAITV(5);                            // retire B(125)
    LGKM0(); BARRIER(); FENCE();
    compute(bb1, &Asb[(NIT - 3) & 3][0]);
    // tile 126: entry [A(127), B(126)x4]
    WAITV(4);
    cvtwrite(aS1, (NIT - 1) & 3);        // buf[127&3]=3
    loadB(bb1, NIT - 1);                 // B(127)
    WAITV(4);                            // retire B(126)
    LGKM0(); BARRIER(); FENCE();
    compute(bb0, &Asb[(NIT - 2) & 3][0]);
    // tile 127: entry [B(127)x4]
    WAITV(0);
    LGKM0(); BARRIER(); FENCE();
    compute(bb1, &Asb[(NIT - 1) & 3][0]);
  }

  // epilogue: G = d[i] * acc -> bf16 LDS, then out[32][256] = G @ W (via WT)
  LGKM0(); BARRIER(); FENCE();
#pragma unroll
  for (int mt = 0; mt < 2; ++mt)
#pragma unroll
    for (int nt = 0; nt < 2; ++nt)
#pragma unroll
      for (int r = 0; r < 4; ++r) {
        const int row = mt * 16 + quad * 4 + r;
        Gs[row][w * 32 + nt * 16 + lan] = f2bf(acc[mt][nt][r] * dsh[row]);
      }
  __syncthreads();

  const int r0w = (w & 1) * 16, j0c = (w >> 1) * 64;
  f32x4 o[4];
#pragma unroll
  for (int nt = 0; nt < 4; ++nt)
#pragma unroll
    for (int c = 0; c < 4; ++c) o[nt][c] = 0.0f;
#pragma unroll
  for (int ks = 0; ks < 8; ++ks) {
    FragU af;
    af.u = *(const uint4*)&Gs[r0w + lan][ks * 32 + quad * 8];
#pragma unroll
    for (int nt = 0; nt < 4; ++nt) {
      FragU bw;
      bw.u = *(const uint4*)&WT[(size_t)(j0c + nt * 16 + lan) * CH + ks * 32 + quad * 8];
      o[nt] = __builtin_amdgcn_mfma_f32_16x16x32_bf16(af.h, bw.h, o[nt], 0, 0, 0);
    }
  }
#pragma unroll
  for (int nt = 0; nt < 4; ++nt)
#pragma unroll
    for (int r = 0; r < 4; ++r)
      out[(size_t)(i0 + r0w + quad * 4 + r) * CH + j0c + nt * 16 + lan] = o[nt][r];
}

extern "C" void kernel_launch(void* const* d_in, const int* in_sizes, int n_in,
                              void* d_out, int out_size, void* d_ws, size_t ws_size,
                              hipStream_t stream) {
  const float* A  = (const float*)d_in[0];
  const float* Dm = (const float*)d_in[1];
  const float* Hm = (const float*)d_in[2];
  const float* Wm = (const float*)d_in[3];
  float* out = (float*)d_out;
  char* ws = (char*)d_ws;
  unsigned short* HT = (unsigned short*)ws;                       // 4 MiB
  unsigned short* WT = (unsigned short*)(ws + (size_t)4194304);   // 128 KiB

  hipLaunchKernelGGL(k_prep, dim3(528), dim3(256), 0, stream, Hm, Dm, Wm, HT, WT);
  hipLaunchKernelGGL(k_fused, dim3(256), dim3(512), 0, stream, A, Dm, HT, WT, out);
}